// Round 5
// baseline (278.556 us; speedup 1.0000x reference)
//
#include <hip/hip_runtime.h>

#define DIM 1024

typedef _Float16 half8  __attribute__((ext_vector_type(8)));
typedef _Float16 half4v __attribute__((ext_vector_type(4)));
typedef float    f32x4  __attribute__((ext_vector_type(4)));

__device__ __forceinline__ int swz(int p) { return p ^ ((p >> 4) & 15); }

__device__ __forceinline__ void gl2lds(const _Float16* g, _Float16* s) {
  __builtin_amdgcn_global_load_lds(
      (const __attribute__((address_space(1))) void*)g,
      (__attribute__((address_space(3))) void*)s, 16, 0, 0);
}

// ---------------- K1: evolve basis columns -> Bt_hi/Bt_lo [n][k] ------------
// Bt[n][k] = (n&1 ? Im : Re) of U[n>>1, k]; hi = fp16(v), lo = fp16(v - hi).
__global__ __launch_bounds__(256) void k_build(
    const float* __restrict__ rx0, const float* __restrict__ ry0,
    const float* __restrict__ ry1, _Float16* __restrict__ BtH,
    _Float16* __restrict__ BtL) {
  __shared__ float2 st[2][4][DIM];          // ping-pong, 4 columns
  __shared__ unsigned short invp[DIM];
  __shared__ float2 rot[30];
  const int t = threadIdx.x;
  const int w = t >> 6;                      // wave = column
  const int l = t & 63;
  const int k0 = blockIdx.x * 4;

  if (t < 30) {
    float th = (t < 10) ? rx0[t] : (t < 20 ? ry0[t - 10] : ry1[t - 20]);
    rot[t] = make_float2(cosf(0.5f * th), sinf(0.5f * th));
  }
  for (int p = t; p < DIM; p += 256) {
    int b = p;                               // inverse of the CNOT-ring map
    #pragma unroll
    for (int j = 9; j >= 0; --j) b ^= ((b >> ((j + 1) % 10)) & 1) << j;
    invp[p] = (unsigned short)b;
  }
  {
    const int k = k0 + w;
    for (int i = 0; i < 16; ++i) {
      int p = l * 16 + i;
      st[0][w][swz(p)] = make_float2(p == k ? 1.f : 0.f, 0.f);
    }
  }
  __syncthreads();

  int cur = 0;

  auto quad = [&](int qbase, bool ph1, bool gather) {
    float2 v[16];
    #pragma unroll
    for (int i = 0; i < 16; ++i) {
      int p = (qbase == 0) ? ((l << 4) | i)
                           : (((l >> 4) << 8) | (i << 4) | (l & 15));
      int sp = gather ? (int)invp[p] : p;
      v[i] = st[cur][w][swz(sp)];
    }
    #pragma unroll
    for (int qq = 0; qq < 4; ++qq) {
      const int q = qbase + qq;
      if (ph1) {                              // RX(rx0_q)
        const float cx = rot[q].x, sx = rot[q].y;
        #pragma unroll
        for (int i = 0; i < 16; ++i) {
          if (i & (1 << qq)) continue;
          const int j = i | (1 << qq);
          float2 a = v[i], b = v[j];
          v[i] = make_float2(cx*a.x + sx*b.y,  cx*a.y - sx*b.x);
          v[j] = make_float2(sx*a.y + cx*b.x, -sx*a.x + cx*b.y);
        }
      }
      const float cy = ph1 ? rot[10+q].x : rot[20+q].x;   // RY
      const float sy = ph1 ? rot[10+q].y : rot[20+q].y;
      #pragma unroll
      for (int i = 0; i < 16; ++i) {
        if (i & (1 << qq)) continue;
        const int j = i | (1 << qq);
        float2 a = v[i], b = v[j];
        v[i] = make_float2(cy*a.x - sy*b.x, cy*a.y - sy*b.y);
        v[j] = make_float2(sy*a.x + cy*b.x, sy*a.y + cy*b.y);
      }
    }
    const int dst = gather ? (cur ^ 1) : cur;
    #pragma unroll
    for (int i = 0; i < 16; ++i) {
      int p = (qbase == 0) ? ((l << 4) | i)
                           : (((l >> 4) << 8) | (i << 4) | (l & 15));
      st[dst][w][swz(p)] = v[i];
    }
    if (gather) cur ^= 1;
    __syncthreads();
  };

  auto duo = [&](bool ph1) {                  // qubits 8,9
    #pragma unroll
    for (int rep = 0; rep < 4; ++rep) {
      const int u = l + rep * 64;
      float2 v[4];
      #pragma unroll
      for (int i = 0; i < 4; ++i) v[i] = st[cur][w][swz((i << 8) | u)];
      #pragma unroll
      for (int qq = 0; qq < 2; ++qq) {
        const int q = 8 + qq;
        if (ph1) {
          const float cx = rot[q].x, sx = rot[q].y;
          #pragma unroll
          for (int i = 0; i < 4; ++i) {
            if (i & (1 << qq)) continue;
            const int j = i | (1 << qq);
            float2 a = v[i], b = v[j];
            v[i] = make_float2(cx*a.x + sx*b.y,  cx*a.y - sx*b.x);
            v[j] = make_float2(sx*a.y + cx*b.x, -sx*a.x + cx*b.y);
          }
        }
        const float cy = ph1 ? rot[10+q].x : rot[20+q].x;
        const float sy = ph1 ? rot[10+q].y : rot[20+q].y;
        #pragma unroll
        for (int i = 0; i < 4; ++i) {
          if (i & (1 << qq)) continue;
          const int j = i | (1 << qq);
          float2 a = v[i], b = v[j];
          v[i] = make_float2(cy*a.x - sy*b.x, cy*a.y - sy*b.y);
          v[j] = make_float2(sy*a.x + cy*b.x, sy*a.y + cy*b.y);
        }
      }
      #pragma unroll
      for (int i = 0; i < 4; ++i) st[cur][w][swz((i << 8) | u)] = v[i];
    }
    __syncthreads();
  };

  quad(0, true, false);  quad(4, true, false);  duo(true);      // phase 1
  for (int L = 0; L < 10; ++L) {
    quad(0, false, true);                    // CNOT perm + RY q0-3
    quad(4, false, false);                   // RY q4-7
    duo(false);                              // RY q8-9
  }

  for (int n = t; n < 2048; n += 256) {      // write Bt[n][k0..k0+3]
    const int m = n >> 1;
    half4v hh, hl;
    #pragma unroll
    for (int c = 0; c < 4; ++c) {
      float2 a = st[cur][c][swz(m)];
      const float v = (n & 1) ? a.y : a.x;
      const _Float16 hi = (_Float16)v;
      hh[c] = hi;
      hl[c] = (_Float16)(v - (float)hi);
    }
    *(half4v*)(BtH + (size_t)n * DIM + k0) = hh;
    *(half4v*)(BtL + (size_t)n * DIM + k0) = hl;
  }
}

// ---------------- K2: per-row inverse norm ----------------------------------
__global__ __launch_bounds__(256) void k_norms(const float* __restrict__ x,
                                               float* __restrict__ invn) {
  const int row = blockIdx.x * 4 + (threadIdx.x >> 6);
  const int l = threadIdx.x & 63;
  const float4* xp = (const float4*)(x + (size_t)row * DIM);
  float ss = 0.f;
  #pragma unroll
  for (int i = 0; i < 4; ++i) {
    const float4 v = xp[l + i * 64];
    ss += v.x*v.x + v.y*v.y + v.z*v.z + v.w*v.w;
  }
  #pragma unroll
  for (int m = 32; m; m >>= 1) ss += __shfl_xor(ss, m);
  if (l == 0) invn[row] = rsqrtf(ss);
}

// ---------------- K3: split-fp16 GEMM + fused EV epilogue -------------------
// acc = Ah*Bh + Al*Bh + Ah*Bl (fp32 MFMA accum) -> ~2^-22 operand precision.
// All LDS tiles [128][64] with chunk-XOR swizzle: 16B chunk c of row r is
// stored at chunk c ^ (r&7). B arrives pre-swizzled via per-lane global src
// address (global_load_lds dest must be linear); A swizzled at ds_write.
template <bool ATOMIC>
__global__ __launch_bounds__(256) void k_gemm(const float* __restrict__ gA,
                                              const _Float16* __restrict__ gBh,
                                              const _Float16* __restrict__ gBl,
                                              const float* __restrict__ invn,
                                              float* __restrict__ partials,
                                              float* __restrict__ out) {
  __shared__ __align__(16) union SM {
    struct { _Float16 Ah[128][64], Al[128][64], Bh[128][64], Bl[128][64]; } s; // 64 KB
    struct { float C[128][65]; float ev[128][16]; } e;                         // 40.5 KB
  } sm;
  const int t = threadIdx.x;
  const int w = t >> 6, l = t & 63;
  const int wm = w & 1, wn = w >> 1;
  const int bid = blockIdx.x;
  const int bm = bid & 127, bn = bid >> 7;   // bm fastest: B-tile L2 reuse

  f32x4 acc[4][4] = {};

  const int arow = bm*128 + (t >> 1);         // global row this thread stages
  const float s = invn[arow];                 // 1/||x||
  const float* aRow = gA + (size_t)arow*DIM + (t & 1)*32;
  const int ar = t >> 1;                      // LDS row for A staging
  const int acb = (t & 1)*4;                  // global chunk base (16B units)
  // B source: lane l stages row (l>>3), global chunk (l&7)^(l>>3) so that the
  // linear LDS write lands chunk c of row r at LDS chunk c^(r&7).
  const size_t bOff = ((size_t)(bn*128 + w*32 + (l>>3)))*DIM + (((l&7)^(l>>3))*8);
  const _Float16* bSrcH = gBh + bOff;
  const _Float16* bSrcL = gBl + bOff;
  _Float16* bDstH = &sm.s.Bh[w*32][0];
  _Float16* bDstL = &sm.s.Bl[w*32][0];

  for (int kt = 0; kt < 16; ++kt) {
    #pragma unroll
    for (int i = 0; i < 4; ++i) {             // B hi+lo: async global->LDS
      gl2lds(bSrcH + (size_t)i*8*DIM + kt*64, bDstH + i*8*64);
      gl2lds(bSrcL + (size_t)i*8*DIM + kt*64, bDstL + i*8*64);
    }
    {                                         // A: fp32 load, scale, split, write
      const float4* ap = (const float4*)(aRow + kt*64);
      float4 f[8];
      #pragma unroll
      for (int i = 0; i < 8; ++i) f[i] = ap[i];
      #pragma unroll
      for (int i = 0; i < 4; ++i) {
        float a[8] = { f[2*i].x*s, f[2*i].y*s, f[2*i].z*s, f[2*i].w*s,
                       f[2*i+1].x*s, f[2*i+1].y*s, f[2*i+1].z*s, f[2*i+1].w*s };
        half8 hh, hl;
        #pragma unroll
        for (int j = 0; j < 8; ++j) {
          const _Float16 hi = (_Float16)a[j];
          hh[j] = hi;
          hl[j] = (_Float16)(a[j] - (float)hi);
        }
        const int c = ((acb + i) ^ (ar & 7)) * 8;   // swizzled LDS chunk
        *(half8*)&sm.s.Ah[ar][c] = hh;
        *(half8*)&sm.s.Al[ar][c] = hl;
      }
    }
    __syncthreads();
    #pragma unroll
    for (int ks = 0; ks < 2; ++ks) {
      half8 afh[4], afl[4], bfh[4], bfl[4];
      #pragma unroll
      for (int mi = 0; mi < 4; ++mi) {
        const int r = wm*64 + mi*16 + (l&15);
        const int c = ((ks*4 + (l>>4)) ^ (l&7)) * 8;  // swizzled read
        afh[mi] = *(const half8*)&sm.s.Ah[r][c];
        afl[mi] = *(const half8*)&sm.s.Al[r][c];
      }
      #pragma unroll
      for (int ni = 0; ni < 4; ++ni) {
        const int r = wn*64 + ni*16 + (l&15);
        const int c = ((ks*4 + (l>>4)) ^ (l&7)) * 8;
        bfh[ni] = *(const half8*)&sm.s.Bh[r][c];
        bfl[ni] = *(const half8*)&sm.s.Bl[r][c];
      }
      #pragma unroll
      for (int mi = 0; mi < 4; ++mi)
        #pragma unroll
        for (int ni = 0; ni < 4; ++ni) {
          acc[mi][ni] = __builtin_amdgcn_mfma_f32_16x16x32_f16(
              afh[mi], bfh[ni], acc[mi][ni], 0, 0, 0);
          acc[mi][ni] = __builtin_amdgcn_mfma_f32_16x16x32_f16(
              afl[mi], bfh[ni], acc[mi][ni], 0, 0, 0);
          acc[mi][ni] = __builtin_amdgcn_mfma_f32_16x16x32_f16(
              afh[mi], bfl[ni], acc[mi][ni], 0, 0, 0);
        }
    }
    __syncthreads();
  }

  float ev[16];
  #pragma unroll
  for (int e = 0; e < 16; ++e) ev[e] = 0.f;
  const int er = t & 127, eh = t >> 7;

  #pragma unroll
  for (int chunk = 0; chunk < 2; ++chunk) {
    if (wn == chunk) {                       // C/D: col=lane&15, row=(lane>>4)*4+reg
      #pragma unroll
      for (int mi = 0; mi < 4; ++mi)
        #pragma unroll
        for (int ni = 0; ni < 4; ++ni)
          #pragma unroll
          for (int r = 0; r < 4; ++r)
            sm.e.C[wm*64 + mi*16 + (l>>4)*4 + r][ni*16 + (l&15)] = acc[mi][ni][r];
    }
    __syncthreads();
    #pragma unroll
    for (int gi = 0; gi < 4; ++gi) {
      const int g = eh*4 + gi;               // 8 cols = 4 m-values x (Re,Im)
      const float* cr = &sm.e.C[er][g*8];
      float yr0=cr[0], yi0=cr[1], yr1=cr[2], yi1=cr[3];
      float yr2=cr[4], yi2=cr[5], yr3=cr[6], yi3=cr[7];
      float n0=yr0*yr0+yi0*yi0, n1=yr1*yr1+yi1*yi1;
      float n2=yr2*yr2+yi2*yi2, n3=yr3*yr3+yi3*yi3;
      float p03r=yr0*yr3+yi0*yi3, p03i=yr0*yi3-yi0*yr3;
      float p12r=yr1*yr2+yi1*yi2, p12i=yr1*yi2-yi1*yr2;
      float p01r=yr0*yr1+yi0*yi1, p01i=yr0*yi1-yi0*yr1;
      float p23r=yr2*yr3+yi2*yi3, p23i=yr2*yi3-yi2*yr3;
      float ns = n0+n1+n2+n3;
      const int m0 = bn*64 + chunk*32 + g*4; // global m base of this group
      ev[0]  += n0 - n1 + n2 - n3;           // Z0
      ev[1]  += n0 + n1 - n2 - n3;           // Z1
      #pragma unroll
      for (int q = 2; q < 10; ++q) ev[q] += ((m0 >> q) & 1) ? -ns : ns;
      ev[10] += 2.f*(p03r + p12r);           // XX
      ev[11] += 2.f*(p12r - p03r);           // YY
      ev[12] += n0 - n1 - n2 + n3;           // ZZ
      ev[13] += 2.f*(p03i + p12i);           // XY
      ev[14] += 2.f*(p01r - p23r);           // XZ
      ev[15] += 2.f*(p01i - p23i);           // YZ
    }
    __syncthreads();
  }
  if (eh == 1) {
    #pragma unroll
    for (int e = 0; e < 16; ++e) sm.e.ev[er][e] = ev[e];
  }
  __syncthreads();
  if (eh == 0) {
    const int row = bm*128 + er;
    if (ATOMIC) {
      #pragma unroll
      for (int e = 0; e < 16; ++e)
        atomicAdd(out + (size_t)row*16 + e, ev[e] + sm.e.ev[er][e]);
    } else {
      float* dst = partials + ((size_t)row*16 + bn)*16;
      #pragma unroll
      for (int e = 0; e < 16; ++e) dst[e] = ev[e] + sm.e.ev[er][e];
    }
  }
}

// ---------------- K4: reduce partials over the 16 n-tiles -------------------
__global__ __launch_bounds__(256) void k_red(const float* __restrict__ partials,
                                             float* __restrict__ out) {
  const int gid = blockIdx.x * 256 + threadIdx.x;   // 262144 = row*16 + ev
  const int row = gid >> 4;
  float s = 0.f;
  #pragma unroll
  for (int bn = 0; bn < 16; ++bn) s += partials[((size_t)row*16 + bn)*16 + (gid & 15)];
  out[gid] = s;
}

extern "C" void kernel_launch(void* const* d_in, const int* in_sizes, int n_in,
                              void* d_out, int out_size, void* d_ws, size_t ws_size,
                              hipStream_t stream) {
  const float* x   = (const float*)d_in[0];
  const float* rx0 = (const float*)d_in[1];
  const float* ry0 = (const float*)d_in[2];
  const float* ry1 = (const float*)d_in[3];
  float* out = (float*)d_out;
  char* ws = (char*)d_ws;
  // ws: BtH 4MB @0; BtL 4MB @4MB; invn 64KB @8MB; partials 16MB @9MB = 25MB.
  _Float16* BtH   = (_Float16*)ws;
  _Float16* BtL   = (_Float16*)(ws + ((size_t)4 << 20));
  float*    invn  = (float*)(ws + ((size_t)8 << 20));
  float*    partials = (float*)(ws + ((size_t)9 << 20));
  const bool use_partials = ws_size >= ((size_t)25 << 20);

  k_build<<<dim3(256),  dim3(256), 0, stream>>>(rx0, ry0, ry1, BtH, BtL);
  k_norms<<<dim3(4096), dim3(256), 0, stream>>>(x, invn);
  if (use_partials) {
    k_gemm<false><<<dim3(2048), dim3(256), 0, stream>>>(x, BtH, BtL, invn, partials, out);
    k_red<<<dim3(1024), dim3(256), 0, stream>>>(partials, out);
  } else {
    // Fallback for small workspace (>=9MB): accumulate EVs atomically.
    hipMemsetAsync(out, 0, (size_t)out_size * sizeof(float), stream);
    k_gemm<true><<<dim3(2048), dim3(256), 0, stream>>>(x, BtH, BtL, invn, partials, out);
  }
}